// Round 20
// baseline (342.901 us; speedup 1.0000x reference)
//
#include <hip/hip_runtime.h>
#include <hip/hip_bf16.h>
#include <cstddef>

typedef unsigned short u16;
typedef __attribute__((ext_vector_type(8))) short bf16x8;
typedef __attribute__((ext_vector_type(4))) float f32x4;

#define C2 0.18033688011112042f   // 0.125 * log2(e)

__device__ __forceinline__ u16 f2b(float f) {
    unsigned u = __builtin_bit_cast(unsigned, f);
    unsigned r = (u + 0x7FFF + ((u >> 16) & 1)) >> 16;
    return (u16)r;
}

__device__ __forceinline__ float exp2a(float x) {
    float r; asm("v_exp_f32 %0, %1" : "=v"(r) : "v"(x)); return r;
}

__device__ __forceinline__ unsigned cvtpk(float lo, float hi) {
    unsigned r; asm("v_cvt_pk_bf16_f32 %0, %1, %2" : "=v"(r) : "v"(lo), "v"(hi));
    return r;
}

__device__ __forceinline__ void gload_lds16(const void* g, void* l) {
    __builtin_amdgcn_global_load_lds(
        (const __attribute__((address_space(1))) unsigned int*)g,
        (__attribute__((address_space(3))) unsigned int*)l, 16, 0, 0);
}

#define VDRAIN() asm volatile("s_waitcnt vmcnt(0)" ::: "memory")
#define SBAR() do { __builtin_amdgcn_sched_barrier(0); __builtin_amdgcn_s_barrier(); } while (0)

// ---------------- fused prep ----------------
__device__ __forceinline__ void transpose_body(
    const float* __restrict__ in, u16* __restrict__ out, int K, int N,
    int bx, int by, float (*t)[33], int tid)
{
    int k0 = by * 32, n0 = bx * 32;
    int tx = tid & 31, ty = tid >> 5;
    #pragma unroll
    for (int p = 0; p < 4; ++p)
        t[ty + 8 * p][tx] = in[(size_t)(k0 + ty + 8 * p) * N + n0 + tx];
    __syncthreads();
    #pragma unroll
    for (int p = 0; p < 4; ++p)
        out[(size_t)(n0 + ty + 8 * p) * K + k0 + tx] = f2b(t[tx][ty + 8 * p]);
}

// copy(new_mem=x) | cvt(pos) | concat | Wkv^T | Wq^T | Wout^T | w2t | zero(acc)
__global__ __launch_bounds__(256) void megaprep(
    const float* __restrict__ pos, u16* __restrict__ peb,
    const float* __restrict__ x, const float* __restrict__ mem,
    const float* __restrict__ cmem, u16* __restrict__ kvin,
    const float* __restrict__ Wkv, u16* __restrict__ wkvt,
    const float* __restrict__ Wq, u16* __restrict__ wqt,
    const float* __restrict__ Wout, u16* __restrict__ woutt,
    const float* __restrict__ convw, u16* __restrict__ w2t,
    float* __restrict__ new_mem, float* __restrict__ acc)
{
    __shared__ float t[32][33];
    const int bid = blockIdx.x, tid = threadIdx.x;
    if (bid == 0 && tid == 0) acc[0] = 0.f;
    if (bid < 4096) {                         // new_mem = x (fp32 copy)
        int i = bid * 256 + tid;
        ((float4*)new_mem)[i] = ((const float4*)x)[i];
    } else if (bid < 6400) {                  // cvt pos
        int i = (bid - 4096) * 256 + tid;
        float4 v = ((const float4*)pos)[i];
        union { u16 s[4]; uint2 u; } pk;
        pk.s[0] = f2b(v.x); pk.s[1] = f2b(v.y); pk.s[2] = f2b(v.z); pk.s[3] = f2b(v.w);
        ((uint2*)peb)[i] = pk.u;
    } else if (bid < 15616) {                 // concat kv_input
        int rowg = bid - 6400;
        int b = rowg / 2304, rr = rowg % 2304;
        const float* src = (rr < 256)  ? cmem + ((size_t)b * 256 + rr) * 1024
                         : (rr < 1280) ? mem  + ((size_t)b * 1024 + (rr - 256)) * 1024
                                       : x    + ((size_t)b * 1024 + (rr - 1280)) * 1024;
        float4 v = ((const float4*)src)[tid];
        union { u16 s[4]; uint2 u; } pk;
        pk.s[0] = f2b(v.x); pk.s[1] = f2b(v.y); pk.s[2] = f2b(v.z); pk.s[3] = f2b(v.w);
        ((uint2*)(kvin + (size_t)rowg * 1024))[tid] = pk.u;
    } else if (bid < 17664) {                 // Wkv^T
        int m = bid - 15616;
        transpose_body(Wkv, wkvt, 1024, 2048, m % 64, m / 64, t, tid);
    } else if (bid < 18688) {                 // Wq^T
        int m = bid - 17664;
        transpose_body(Wq, wqt, 1024, 1024, m % 32, m / 32, t, tid);
    } else if (bid < 19712) {                 // Wout^T
        int m = bid - 18688;
        transpose_body(Wout, woutt, 1024, 1024, m % 32, m / 32, t, tid);
    } else {                                  // w2t
        int m = bid - 19712;                  // 4096 blocks
        int pidx = m * 256 + tid;
        int o = pidx >> 10, i = pidx & 1023;
        float4 v = *(const float4*)(convw + ((size_t)o << 12) + 4 * i);
        size_t base = (size_t)o * 4096 + i;
        w2t[base]        = f2b(v.x);
        w2t[base + 1024] = f2b(v.y);
        w2t[base + 2048] = f2b(v.z);
        w2t[base + 3072] = f2b(v.w);
    }
}

// ---------------- bf16 MFMA GEMM body (XCD-bijective linear decode) ----------------
__device__ __forceinline__ void gemm_body(
    const u16* __restrict__ A, const u16* __restrict__ Bt,
    const float* __restrict__ bias, float* __restrict__ Cf,
    u16* __restrict__ Cb, int N, int K, float cscale,
    int apad, int ashift, int nxshift, int nyper, int id,
    u16* Al, u16* Bl)
{
    const int tid = threadIdx.x, w = tid >> 6, lane = tid & 63;
    const int lr = lane & 15, lg = lane >> 4;
    const int xcd = id & 7, s = id >> 3;
    const int bx = s & ((1 << nxshift) - 1);
    const int by = nyper * xcd + (s >> nxshift);
    const int bm0 = by * 128, bn0 = bx * 128;
    const int wr = (w >> 1) * 64, wc = (w & 1) * 64;

    f32x4 acc[4][4];
    const f32x4 z = {0.f, 0.f, 0.f, 0.f};
    #pragma unroll
    for (int mb = 0; mb < 4; ++mb)
        #pragma unroll
        for (int nb = 0; nb < 4; ++nb) acc[mb][nb] = z;

    for (int k0 = 0; k0 < K; k0 += 32) {
        __syncthreads();
        #pragma unroll
        for (int q = 0; q < 2; ++q) {
            int chunk = w * 2 + q;
            int row = bm0 + chunk * 16 + (lane >> 2);
            int arow = row + ((row >> ashift) * apad);
            int sg = (lane & 3) * 8;
            gload_lds16(A + (size_t)arow * K + k0 + sg, &Al[chunk * 512]);
            gload_lds16(Bt + (size_t)(bn0 + chunk * 16 + (lane >> 2)) * K + k0 + sg, &Bl[chunk * 512]);
        }
        __syncthreads();
        bf16x8 af[4], bf[4];
        #pragma unroll
        for (int mb = 0; mb < 4; ++mb)
            af[mb] = *(const bf16x8*)&Al[(wr + mb * 16 + lr) * 32 + lg * 8];
        #pragma unroll
        for (int nb = 0; nb < 4; ++nb)
            bf[nb] = *(const bf16x8*)&Bl[(wc + nb * 16 + lr) * 32 + lg * 8];
        #pragma unroll
        for (int mb = 0; mb < 4; ++mb)
            #pragma unroll
            for (int nb = 0; nb < 4; ++nb)
                acc[mb][nb] = __builtin_amdgcn_mfma_f32_16x16x32_bf16(
                    af[mb], bf[nb], acc[mb][nb], 0, 0, 0);
    }

    #pragma unroll
    for (int mb = 0; mb < 4; ++mb)
        #pragma unroll
        for (int nb = 0; nb < 4; ++nb)
            #pragma unroll
            for (int jr = 0; jr < 4; ++jr) {
                int row = bm0 + wr + mb * 16 + lg * 4 + jr;
                int col = bn0 + wc + nb * 16 + lr;
                float v = acc[mb][nb][jr] + (bias ? bias[col] : 0.f);
                if (Cf) Cf[(size_t)row * N + col] = v;
                if (Cb) Cb[(size_t)row * N + col] = f2b(v * cscale);
            }
}

// LPT order: compress (64, K=4096 longest) | Q (256) | kv (1152)
__global__ __launch_bounds__(256) void gemm_stage1(
    const u16* __restrict__ kvin, const u16* __restrict__ wkvt,
    const u16* __restrict__ wqt, const u16* __restrict__ w2t,
    const float* __restrict__ convb, u16* __restrict__ kvb,
    u16* __restrict__ qb, float* __restrict__ new_cmem, u16* __restrict__ cmpb)
{
    __shared__ u16 Al[128 * 32];
    __shared__ u16 Bl[128 * 32];
    const int id = blockIdx.x;
    if (id < 64)
        gemm_body(kvin + (size_t)256 * 1024, w2t, convb, new_cmem, cmpb,
                  1024, 4096, 1.f, 320, 8, 3, 1, id, Al, Bl);
    else if (id < 320)
        gemm_body(kvin + (size_t)1280 * 1024, wqt, nullptr, nullptr, qb,
                  1024, 1024, C2, 1280, 10, 3, 4, id - 64, Al, Bl);
    else
        gemm_body(kvin, wkvt, nullptr, nullptr, kvb, 2048, 1024, 1.f,
                  0, 10, 4, 9, id - 320, Al, Bl);
}

__device__ __forceinline__ void transpose_v_body(
    const u16* __restrict__ src, int R, u16* __restrict__ dst,
    int bh, int j0, u16* t, int tid)
{
    const int b = bh >> 4, h = bh & 15;
    #pragma unroll
    for (int p = 0; p < 2; ++p) {
        int idx = tid + p * 256;
        int j = idx >> 3, c = idx & 7;
        uint4 v = *(const uint4*)(src + ((size_t)(b * R + j0 + j)) * 2048 + 1024 + h * 64 + c * 8);
        const u16* vv = (const u16*)&v;
        #pragma unroll
        for (int u2 = 0; u2 < 8; ++u2) t[j * 65 + c * 8 + u2] = vv[u2];
    }
    __syncthreads();
    #pragma unroll
    for (int p = 0; p < 2; ++p) {
        int idx = tid + p * 256;
        int jc = idx & 7, d = idx >> 3;
        union { u16 s[8]; uint4 u; } pk;
        #pragma unroll
        for (int u2 = 0; u2 < 8; ++u2) pk.s[u2] = t[(jc * 8 + u2) * 65 + d];
        *(uint4*)(dst + ((size_t)(bh * 64 + d)) * (size_t)R + j0 + jc * 8) = pk.u;
    }
}

// ckcv GEMM (128 blocks) | main V transpose (2304 blocks)
__global__ __launch_bounds__(256) void gemm_ckcv_tv(
    const u16* __restrict__ cmpb, const u16* __restrict__ wkvt,
    u16* __restrict__ ckcvb, const u16* __restrict__ kvb, u16* __restrict__ vt)
{
    __shared__ u16 shmem[128 * 64];
    const int id = blockIdx.x;
    if (id < 128) {
        gemm_body(cmpb, wkvt, nullptr, nullptr, ckcvb, 2048, 1024, 1.f,
                  0, 10, 4, 1, id, shmem, shmem + 4096);
    } else {
        int m = id - 128;
        transpose_v_body(kvb, 2304, vt, m / 36, (m % 36) * 64, shmem, threadIdx.x);
    }
}

// compressed V transpose (256 blocks)
__global__ __launch_bounds__(256) void transpose_cvt(
    const u16* __restrict__ ckcvb, u16* __restrict__ cvt)
{
    __shared__ u16 t[64 * 65];
    int m = blockIdx.x;
    transpose_v_body(ckcvb, 256, cvt, m / 4, (m % 4) * 64, t, threadIdx.x);
}

// out GEMM + aux finish
__global__ __launch_bounds__(256) void gemm_out(
    const u16* __restrict__ aob, const u16* __restrict__ woutt,
    const float* __restrict__ bout, float* __restrict__ logits,
    const float* __restrict__ acc, float* __restrict__ aux_out)
{
    __shared__ u16 Al[128 * 32];
    __shared__ u16 Bl[128 * 32];
    if (blockIdx.x == 0 && threadIdx.x == 0)
        aux_out[0] = acc[0] * (1.0f / 4194304.0f);
    gemm_body(aob, woutt, bout, logits, nullptr, 1024, 1024, 1.f,
              0, 10, 3, 4, blockIdx.x, Al, Bl);
}

// ---------------- fused main attention + FULL aux loss (round-18 verbatim) ----------------
// V double-buffered: V(t+1) staged with K(t+1)/PE(t+1) right after barrier B
// into vbuf[vcur^1] (PV reads vbuf[vcur]) -> B needs no vm drain; the single
// remaining drain (before C) has the softmax+PV+aux phase as cover.
// NOTE: natural register allocation (~176 unified/wave -> 2 blocks/CU).
// __launch_bounds__(256,3) is TOXIC here (NaN, bisected rounds 16/19):
// forced spills interleave scratch vmem with the hand-placed vmcnt fences.
__global__ __launch_bounds__(256) void attn_main_fused(
    const u16* __restrict__ qb, const u16* __restrict__ kvb,
    const u16* __restrict__ vt, const u16* __restrict__ peb,
    const u16* __restrict__ ckcv, const u16* __restrict__ cvt,
    u16* __restrict__ outb, float* __restrict__ acc)
{
    __shared__ u16 kbuf[64 * 64];
    __shared__ u16 vbuf[2][64 * 64];
    __shared__ u16 pering[128 * 64];
    __shared__ u16 pls[4][1024];
    __shared__ float red[4];

    const int tid = threadIdx.x;
    const int w = tid >> 6, lane = tid & 63;
    const int lr = lane & 15, lg = lane >> 4;
    const int rl = lane >> 3, cch = lane & 7;
    const int id = blockIdx.x;
    const int slot = id >> 3;
    const int bh = (id & 7) + ((slot >> 4) << 3);
    const int b = bh >> 4, h = bh & 15;
    const int i0 = (15 - (slot & 15)) * 64;   // LPT: longest first
    const int iw = i0 + 16 * w;
    const int jb0 = 960 - i0;

    const int lrh = lr >> 3, lrm = lr & 7;
    int pwidx[4], pridx[2];
    #pragma unroll
    for (int nb = 0; nb < 4; ++nb)
        pwidx[nb] = (((nb * 2 + lrh) ^ (lg * 2)) * 8) + lrm;
    #pragma unroll
    for (int ks = 0; ks < 2; ++ks)
        pridx[ks] = lr * 64 + (((ks * 4 + lg) ^ ((lr >> 2) * 2)) * 8);

    bf16x8 qf[2];
    #pragma unroll
    for (int ks = 0; ks < 2; ++ks)
        qf[ks] = *(const bf16x8*)(qb + ((size_t)(b * 1024 + iw + lr)) * 1024
                                  + h * 64 + ks * 32 + lg * 8);

    const f32x4 z = {0.f, 0.f, 0.f, 0.f};
    f32x4 od[4], od2[4];
    float lloc[4], ll2[4];
    #pragma unroll
    for (int nb = 0; nb < 4; ++nb) { od[nb] = z; od2[nb] = z; }
    #pragma unroll
    for (int jr = 0; jr < 4; ++jr) { lloc[jr] = 0.f; ll2[jr] = 0.f; }

    // ---- prologue: K(0), V(0)->vbuf[0], full 128-row PE band ----
    #pragma unroll
    for (int q = 0; q < 2; ++q) {
        int row = 16 * w + 8 * q + rl;
        gload_lds16(kvb + ((size_t)(b * 2304 + row)) * 2048 + h * 64 + ((cch ^ rl) * 8),
                    &kbuf[(16 * w + 8 * q) * 64]);
        gload_lds16(vt + ((size_t)(bh * 64 + row)) * 2304 + ((cch ^ rl) * 8),
                    &vbuf[0][(16 * w + 8 * q) * 64]);
    }
    #pragma unroll
    for (int q = 0; q < 4; ++q) {
        int rr = 32 * w + 8 * q;
        int a = jb0 + rr + rl;
        int srow = a > 2303 ? 2303 : a;
        gload_lds16(peb + ((size_t)(h * 2304 + srow)) * 64 + ((cch ^ rl) * 8),
                    &pering[((jb0 + rr) & 127) * 64]);
    }
    VDRAIN();
    __syncthreads();

    int vcur = 0;
    const int nt = ((i0 + 1343) >> 6) + 1;
    for (int t = 0; t < nt; ++t) {
        const int j0 = t * 64;
        const int jb = jb0 + j0;
        const bool more = (t + 1 < nt);

        f32x4 qk[4], qp[5];
        #pragma unroll
        for (int nb = 0; nb < 4; ++nb) qk[nb] = z;
        #pragma unroll
        for (int f = 0; f < 5; ++f) qp[f] = z;
        __builtin_amdgcn_s_setprio(1);
        #pragma unroll
        for (int ks = 0; ks < 2; ++ks) {
            #pragma unroll
            for (int nb = 0; nb < 4; ++nb) {
                int row = nb * 16 + lr;
                bf16x8 kb = *(const bf16x8*)&kbuf[row * 64 + (((4 * ks + lg) ^ (row & 7)) * 8)];
                qk[nb] = __builtin_amdgcn_mfma_f32_16x16x32_bf16(qf[ks], kb, qk[nb], 0, 0, 0);
            }
            #pragma unroll
            for (int f = 0; f < 5; ++f) {
                int rel = 48 - 16 * w + f * 16 + lr;
                int slotp = (jb + rel) & 127;
                bf16x8 pb = *(const bf16x8*)&pering[slotp * 64 + (((4 * ks + lg) ^ (slotp & 7)) * 8)];
                qp[f] = __builtin_amdgcn_mfma_f32_16x16x32_bf16(qf[ks], pb, qp[f], 0, 0, 0);
            }
        }
        __builtin_amdgcn_s_setprio(0);

        SBAR();     // B: certifies kbuf/pering reads of tile t (no vm drain needed)

        if (more) { // stage K(t+1), PE(t+1), V(t+1)->vbuf[vcur^1]
            const int j0n = j0 + 64;
            #pragma unroll
            for (int q = 0; q < 2; ++q) {
                int row = 16 * w + 8 * q + rl;
                gload_lds16(kvb + ((size_t)(b * 2304 + j0n + row)) * 2048 + h * 64 + ((cch ^ rl) * 8),
                            &kbuf[(16 * w + 8 * q) * 64]);
                gload_lds16(vt + ((size_t)(bh * 64 + row)) * 2304 + j0n + ((cch ^ rl) * 8),
                            &vbuf[vcur ^ 1][(16 * w + 8 * q) * 64]);
            }
            const int A0 = jb + 128;
            #pragma unroll
            for (int q = 0; q < 2; ++q) {
                int rr = A0 + 16 * w + 8 * q;
                int a = rr + rl;
                int srow = a > 2303 ? 2303 : a;
                gload_lds16(peb + ((size_t)(h * 2304 + srow)) * 64 + ((cch ^ rl) * 8),
                            &pering[(rr & 127) * 64]);
            }
        }

        const bool nomask = (j0 + 63 <= iw + 1280);
        #pragma unroll
        for (int jr = 0; jr < 4; ++jr) {
            const int r = lg * 4 + jr;
            const int ia = iw + r;
            const int src = (lane & 48) | ((lr + 15 - r) & 15);
            float rot0 = __shfl(qp[0][jr], src);
            float rot1 = __shfl(qp[1][jr], src);
            float rot2 = __shfl(qp[2][jr], src);
            float rot3 = __shfl(qp[3][jr], src);
            float rot4 = __shfl(qp[4][jr], src);
            const bool hi = (lr > r);
            float s0 = qk[0][jr] + (hi ? rot1 : rot0);
            float s1 = qk[1][jr] + (hi ? rot2 : rot1);
            float s2 = qk[2][jr] + (hi ? rot3 : rot2);
            float s3 = qk[3][jr] + (hi ? rot4 : rot3);
            if (!nomask) {
                s0 = (j0 + lr      <= ia + 1280) ? s0 : -1e30f;
                s1 = (j0 + lr + 16 <= ia + 1280) ? s1 : -1e30f;
                s2 = (j0 + lr + 32 <= ia + 1280) ? s2 : -1e30f;
                s3 = (j0 + lr + 48 <= ia + 1280) ? s3 : -1e30f;
            }
            float p0 = exp2a(s0), p1 = exp2a(s1);
            float p2 = exp2a(s2), p3 = exp2a(s3);
            unsigned pkA = cvtpk(p0, p1), pkB = cvtpk(p2, p3);
            u16* pw = &pls[w][r * 64];
            pw[pwidx[0]] = (u16)pkA; pw[pwidx[1]] = (u16)(pkA >> 16);
            pw[pwidx[2]] = (u16)pkB; pw[pwidx[3]] = (u16)(pkB >> 16);
            lloc[jr] += (p0 + p1) + (p2 + p3);
        }

        __builtin_amdgcn_s_setprio(1);
        #pragma unroll
        for (int ks = 0; ks < 2; ++ks) {
            bf16x8 pa = *(const bf16x8*)&pls[w][pridx[ks]];
            #pragma unroll
            for (int nb = 0; nb < 4; ++nb) {
                int d = nb * 16 + lr;
                bf16x8 vb = *(const bf16x8*)&vbuf[vcur][d * 64 + (((4 * ks + lg) ^ (d & 7)) * 8)];
                od[nb] = __builtin_amdgcn_mfma_f32_16x16x32_bf16(pa, vb, od[nb], 0, 0, 0);
            }
        }
        __builtin_amdgcn_s_setprio(0);

        if (t >= 4 && t <= 19) {
            #pragma unroll
            for (int jr = 0; jr < 4; ++jr) {
                const int r = lg * 4 + jr;
                float p0 = exp2a(qk[0][jr]), p1 = exp2a(qk[1][jr]);
                float p2 = exp2a(qk[2][jr]), p3 = exp2a(qk[3][jr]);
                unsigned pkA = cvtpk(p0, p1), pkB = cvtpk(p2, p3);
                u16* pw = &pls[w][r * 64];
                pw[pwidx[0]] = (u16)pkA; pw[pwidx[1]] = (u16)(pkA >> 16);
                pw[pwidx[2]] = (u16)pkB; pw[pwidx[3]] = (u16)(pkB >> 16);
                ll2[jr] += (p0 + p1) + (p2 + p3);
            }
            __builtin_amdgcn_s_setprio(1);
            #pragma unroll
            for (int ks = 0; ks < 2; ++ks) {
                bf16x8 pa = *(const bf16x8*)&pls[w][pridx[ks]];
                #pragma unroll
                for (int nb = 0; nb < 4; ++nb) {
                    int d = nb * 16 + lr;
                    bf16x8 vb = *(const bf16x8*)&vbuf[vcur][d * 64 + (((4 * ks + lg) ^ (d & 7)) * 8)];
                    od2[nb] = __builtin_amdgcn_mfma_f32_16x16x32_bf16(pa, vb, od2[nb], 0, 0, 0);
                }
            }
            __builtin_amdgcn_s_setprio(0);
        }

        VDRAIN();   // retire own K/PE/V(t+1) loads
        SBAR();     // C: publishes kbuf=K(t+1), pering, vbuf[vcur^1]=V(t+1)
        vcur ^= 1;
    }

    #pragma unroll
    for (int jr = 0; jr < 4; ++jr) {
        float l = lloc[jr];
        #pragma unroll
        for (int mk = 1; mk < 16; mk <<= 1) l += __shfl_xor(l, mk);
        float inv = 1.f / l;
        int ia = iw + lg * 4 + jr;
        #pragma unroll
        for (int nb = 0; nb < 4; ++nb)
            outb[((size_t)(b * 1024 + ia)) * 1024 + h * 64 + nb * 16 + lr] =
                f2b(od[nb][jr] * inv);
    }
    #pragma unroll
    for (int jr = 0; jr < 4; ++jr) {
        float l = ll2[jr];
        #pragma unroll
        for (int mk = 1; mk < 16; mk <<= 1) l += __shfl_xor(l, mk);
        float inv = 1.f / l;
        #pragma unroll
        for (int nb = 0; nb < 4; ++nb) od2[nb][jr] *= inv;
    }

    // ---- aux phase-1: compressed KV (4 tiles), vbuf[0] ----
    #pragma unroll
    for (int nb = 0; nb < 4; ++nb) od[nb] = z;
    #pragma unroll
    for (int jr = 0; jr < 4; ++jr) lloc[jr] = 0.f;
    const u16* kbase = ckcv + ((size_t)(b * 256)) * 2048 + h * 64;
    const u16* vbase = cvt + ((size_t)(bh * 64)) * 256;

    for (int t = 0; t < 4; ++t) {
        const int j0 = t * 64;
        __syncthreads();
        #pragma unroll
        for (int q = 0; q < 2; ++q) {
            int row = 16 * w + 8 * q + rl;
            gload_lds16(kbase + (size_t)(j0 + row) * 2048 + ((cch ^ rl) * 8),
                        &kbuf[(16 * w + 8 * q) * 64]);
            gload_lds16(vbase + (size_t)row * 256 + j0 + ((cch ^ rl) * 8),
                        &vbuf[0][(16 * w + 8 * q) * 64]);
        }
        VDRAIN();
        __syncthreads();

        f32x4 qk[4];
        #pragma unroll
        for (int nb = 0; nb < 4; ++nb) qk[nb] = z;
        #pragma unroll
        for (int ks = 0; ks < 2; ++ks)
            #pragma unroll
            for (int nb = 0; nb < 4; ++nb) {
                int row = nb * 16 + lr;
                bf16x8 kb = *(const bf16x8*)&kbuf[row * 64 + (((4 * ks + lg) ^ (row & 7)) * 8)];
                qk[nb] = __builtin_amdgcn_mfma_f32_16x16x32_bf16(qf[ks], kb, qk[nb], 0, 0, 0);
            }

        #pragma unroll
        for (int jr = 0; jr < 4; ++jr) {
            const int r = lg * 4 + jr;
            float p0 = exp2a(qk[0][jr]), p1 = exp2a(qk[1][jr]);
            float p2 = exp2a(qk[2][jr]), p3 = exp2a(qk[3][jr]);
            unsigned pkA = cvtpk(p0, p1), pkB = cvtpk(p2, p3);
            u16* pw = &pls[w][r * 64];
            pw[pwidx[0]] = (u16)pkA; pw[pwidx[1]] = (u16)(pkA >> 16);
            pw[pwidx[2]] = (u16)pkB; pw[pwidx[3]] = (u16)(pkB >> 16);
            lloc[jr] += (p0 + p1) + (p2 + p3);
        }

        #pragma unroll
        for (int ks = 0; ks < 2; ++ks) {
            bf16x8 pa = *(const bf16x8*)&pls[w][pridx[ks]];
            #pragma unroll
            for (int nb = 0; nb < 4; ++nb) {
                int d = nb * 16 + lr;
                bf16x8 vb = *(const bf16x8*)&vbuf[0][d * 64 + (((4 * ks + lg) ^ (d & 7)) * 8)];
                od[nb] = __builtin_amdgcn_mfma_f32_16x16x32_bf16(pa, vb, od[nb], 0, 0, 0);
            }
        }
    }

    float local = 0.f;
    #pragma unroll
    for (int jr = 0; jr < 4; ++jr) {
        float l = lloc[jr];
        #pragma unroll
        for (int mk = 1; mk < 16; mk <<= 1) l += __shfl_xor(l, mk);
        float inv = 1.f / l;
        #pragma unroll
        for (int nb = 0; nb < 4; ++nb) {
            float d = od2[nb][jr] - od[nb][jr] * inv;
            local += d * d;
        }
    }
    #pragma unroll
    for (int mk = 1; mk < 64; mk <<= 1) local += __shfl_xor(local, mk);
    if (lane == 0) red[w] = local;
    __syncthreads();
    if (tid == 0) atomicAdd(acc, red[0] + red[1] + red[2] + red[3]);
}

// ---------------- launch ----------------
extern "C" void kernel_launch(void* const* d_in, const int* in_sizes, int n_in,
                              void* d_out, int out_size, void* d_ws, size_t ws_size,
                              hipStream_t stream)
{
    const float* x     = (const float*)d_in[0];
    const float* mem   = (const float*)d_in[1];
    const float* cmem  = (const float*)d_in[2];
    const float* pos   = (const float*)d_in[3];
    const float* Wq    = (const float*)d_in[5];
    const float* Wkv   = (const float*)d_in[6];
    const float* Wout  = (const float*)d_in[7];
    const float* bout  = (const float*)d_in[8];
    const float* convw = (const float*)d_in[9];
    const float* convb = (const float*)d_in[10];

    float* out      = (float*)d_out;
    float* logits   = out;
    float* new_mem  = out + 4194304;
    float* new_cmem = out + 8388608;
    float* aux_out  = out + 9437184;

    char* p = (char*)d_ws;
    u16* kvb   = (u16*)p; p += (size_t)9216 * 2048 * 2;
    u16* qb    = (u16*)p; p += (size_t)4096 * 1024 * 2;
    u16* kvin  = (u16*)p; p += (size_t)9216 * 1024 * 2;   // becomes vt in L3
    u16* wkvt  = (u16*)p; p += (size_t)2048 * 1024 * 2;
    u16* wqt   = (u16*)p; p += (size_t)1024 * 1024 * 2;
    u16* woutt = (u16*)p; p += (size_t)1024 * 1024 * 2;
    u16* w2t   = (u16*)p; p += (size_t)1024 * 4096 * 2;   // becomes cvt in L4
    u16* peb   = (u16*)p; p += (size_t)16 * 2304 * 64 * 2;
    u16* xb    = (u16*)p; p += (size_t)4096 * 1024 * 2;   // spare
    u16* memb  = (u16*)p; p += (size_t)4096 * 1024 * 2;   // spare
    u16* cmpb  = (u16*)p; p += (size_t)1024 * 1024 * 2;
    u16* ckcvb = (u16*)p; p += (size_t)1024 * 2048 * 2;
    u16* aob   = (u16*)p; p += (size_t)4096 * 1024 * 2;
    float* acc = (float*)p;
    u16* vt   = kvin;
    u16* cvt  = w2t;
    (void)xb; (void)memb;

    // L1: copy | cvt | concat | transposes | w2t | zero acc (23808 blocks)
    megaprep<<<23808, 256, 0, stream>>>(pos, peb, x, mem, cmem, kvin,
                                        Wkv, wkvt, Wq, wqt, Wout, woutt,
                                        convw, w2t, new_mem, acc);

    // L2: compress | Q | kv GEMMs, LPT-ordered (1472 blocks)
    gemm_stage1<<<1472, 256, 0, stream>>>(kvin, wkvt, wqt, w2t, convb,
                                          kvb, qb, new_cmem, cmpb);

    // L3: ckcv GEMM | main V transpose (2432 blocks)
    gemm_ckcv_tv<<<2432, 256, 0, stream>>>(cmpb, wkvt, ckcvb, kvb, vt);

    // L4: compressed V transpose
    transpose_cvt<<<256, 256, 0, stream>>>(ckcvb, cvt);

    // L5: fused attention + aux loss
    attn_main_fused<<<1024, 256, 0, stream>>>(qb, kvb, vt, peb, ckcvb, cvt, aob, acc);

    // L6: logits GEMM + aux finish
    gemm_out<<<256, 256, 0, stream>>>(aob, woutt, bout, logits, acc, aux_out);
}